// Round 18
// baseline (932.045 us; speedup 1.0000x reference)
//
#include <hip/hip_runtime.h>
#include <math.h>

// ---------------------------------------------------------------------------
// MambaSpike forward: SNN conv frontend + rate smoothing + 4 mamba blocks.
// All fp32. LIF membrane scans are the ONLY sequential-in-T parts and are
// elementwise; convs/GEMMs are batched over B*T=512.
// R18: R15/R17 base (928us). Added k_gemm128 (128x128 tile) ONLY for the
// HBM-bound input GEMM (K=16384; 64-tile re-reads 528MB, 128-tile 264MB).
// in/out-proj keep the 64x64/BK=32 high-occupancy kernel (R16 showed the
// 128-tile loses on the small L2-resident GEMMs). Ascending-k order in both
// -> input GEMM bit-identical; absmax unchanged.
// ---------------------------------------------------------------------------

static constexpr int TT = 64;
static constexpr float BETA = 0.9f, THR = 1.0f;

// ---------------- frontend ----------------

// conv1 (2->32ch, 3x3 SAME on 64x64) + 2x2 maxpool, fused. Block per (b,t).
__global__ __launch_bounds__(256) void k_conv1pool(const float* __restrict__ x,
    const float* __restrict__ w, const float* __restrict__ bias, float* __restrict__ out)
{
    __shared__ float sI[2 * 66 * 76];   // [ci][row+1][col+4], halo = 0
    __shared__ float sW[576];
    const int bt = blockIdx.x;
    const int tid = threadIdx.x;
    for (int i = tid; i < 2 * 66 * 76; i += 256) sI[i] = 0.f;
    for (int i = tid; i < 576; i += 256) sW[i] = w[i];
    __syncthreads();
    const float* img = x + (size_t)bt * 8192;
    for (int i = tid; i < 2048; i += 256) {
        float4 v4 = ((const float4*)img)[i];
        int lin = i * 4;
        int ci = lin >> 12, rc = lin & 4095;
        int r = rc >> 6, c = rc & 63;
        *(float4*)&sI[ci * 5016 + (r + 1) * 76 + (c + 4)] = v4;
    }
    __syncthreads();
    const int oh = tid >> 3;           // pooled row 0..31
    const int p8 = (tid & 7) * 8;
    float v[2][4][10];
    #pragma unroll
    for (int ci = 0; ci < 2; ++ci) {
        #pragma unroll
        for (int dr = 0; dr < 4; ++dr) {
            const float* rp = &sI[ci * 5016 + (2 * oh + dr) * 76 + p8];
            float2 a  = *(const float2*)&rp[2];
            float4 b4 = *(const float4*)&rp[4];
            float4 c4 = *(const float4*)&rp[8];
            float2 e  = *(const float2*)&rp[12];
            v[ci][dr][0] = a.y;
            v[ci][dr][1] = b4.x; v[ci][dr][2] = b4.y; v[ci][dr][3] = b4.z; v[ci][dr][4] = b4.w;
            v[ci][dr][5] = c4.x; v[ci][dr][6] = c4.y; v[ci][dr][7] = c4.z; v[ci][dr][8] = c4.w;
            v[ci][dr][9] = e.x;
        }
    }
    const int ow0 = (tid & 7) * 4;
    float* obase = out + (size_t)bt * 32768;
    for (int co = 0; co < 32; ++co) {
        float pos[2][8];
        #pragma unroll
        for (int i = 0; i < 2; ++i)
            #pragma unroll
            for (int j = 0; j < 8; ++j) pos[i][j] = 0.f;
        #pragma unroll
        for (int ci = 0; ci < 2; ++ci) {
            const float* wp = &sW[(co * 2 + ci) * 9];
            float w0=wp[0],w1=wp[1],w2=wp[2],w3=wp[3],w4=wp[4],w5=wp[5],w6=wp[6],w7=wp[7],w8=wp[8];
            #pragma unroll
            for (int pr = 0; pr < 2; ++pr)
                #pragma unroll
                for (int pc = 0; pc < 8; ++pc)
                    pos[pr][pc] += v[ci][pr][pc]*w0 + v[ci][pr][pc+1]*w1 + v[ci][pr][pc+2]*w2
                                 + v[ci][pr+1][pc]*w3 + v[ci][pr+1][pc+1]*w4 + v[ci][pr+1][pc+2]*w5
                                 + v[ci][pr+2][pc]*w6 + v[ci][pr+2][pc+1]*w7 + v[ci][pr+2][pc+2]*w8;
        }
        float b0 = bias[co];
        float4 o;
        o.x = fmaxf(fmaxf(pos[0][0], pos[0][1]), fmaxf(pos[1][0], pos[1][1])) + b0;
        o.y = fmaxf(fmaxf(pos[0][2], pos[0][3]), fmaxf(pos[1][2], pos[1][3])) + b0;
        o.z = fmaxf(fmaxf(pos[0][4], pos[0][5]), fmaxf(pos[1][4], pos[1][5])) + b0;
        o.w = fmaxf(fmaxf(pos[0][6], pos[0][7]), fmaxf(pos[1][6], pos[1][7])) + b0;
        *(float4*)&obase[co * 1024 + oh * 32 + ow0] = o;
    }
}

// generic LIF scan: thread per (b, chw) position, loop t.  spk = (m>THR)
__global__ __launch_bounds__(256) void k_lif(const float* __restrict__ cur,
                                             float* __restrict__ spk, int chw)
{
    int idx = blockIdx.x * 256 + threadIdx.x;
    int b = idx / chw, p = idx % chw;
    const float* cp = cur + (size_t)b * TT * chw + p;
    float* sp = spk + (size_t)b * TT * chw + p;
    float m = 0.f;
    for (int t = 0; t < TT; ++t) {
        float c = cp[(size_t)t * chw];
        float reset = (m > THR) ? THR : 0.f;
        m = BETA * m + c - reset;
        sp[(size_t)t * chw] = (m > THR) ? 1.f : 0.f;
    }
}

// conv2 (32->32ch, 3x3 SAME on 32x32) + fused 2x2 maxpool + bias. [R14/R15]
__global__ __launch_bounds__(256) void k_conv2(const float* __restrict__ s1,
    const float* __restrict__ w, const float* __restrict__ bias, float* __restrict__ out)
{
    __shared__ float sI[2 * 34 * 40];   // [ci2][r+1][c+4], halo = 0 (10.9KB)
    __shared__ float sW2[32 * 8 * 12];  // [ci32][co8][12] (k 0..8 used)
    const int bt = blockIdx.y;
    const int co0 = blockIdx.x * 8;
    const int tid = threadIdx.x;
    for (int i = tid; i < 2 * 34 * 40; i += 256) sI[i] = 0.f;
    for (int i = tid; i < 2304; i += 256) {       // all weights upfront
        int ci = i / 72, rest = i % 72;
        int co = rest / 9, k = rest % 9;
        sW2[(ci * 8 + co) * 12 + k] = w[((co0 + co) * 32 + ci) * 9 + k];
    }
    const int cc = tid & 31;
    const int g8 = ((tid >> 5) & 3) * 8;    // row base 0,8,16,24
    const int cq = (tid >> 7) * 4;          // local co base 0 or 4
    float acc[4][8] = {};
    const float* img = s1 + (size_t)bt * 32768;

    float4 pf0, pf1;                        // 2ci chunk = 512 f4
    auto loadStage = [&](int chunk) {
        const float4* src = (const float4*)(img + chunk * 2048);
        pf0 = src[tid]; pf1 = src[tid + 256];
    };
    auto writeStage = [&]() {
        #pragma unroll
        for (int j = 0; j < 2; ++j) {
            float4 v4 = j ? pf1 : pf0;
            int lin = (tid + j * 256) * 4;
            int ci = lin >> 10, rc = lin & 1023;   // ci 0..1
            int r = rc >> 5, c = rc & 31;
            *(float4*)&sI[ci * 1360 + (r + 1) * 40 + (c + 4)] = v4;
        }
    };

    loadStage(0);
    __syncthreads();            // zero-init + weight stage complete
    for (int chunk = 0; chunk < 16; ++chunk) {
        writeStage();
        if (chunk < 15) loadStage(chunk + 1);   // overlaps compute below
        __syncthreads();
        #pragma unroll
        for (int ci2 = 0; ci2 < 2; ++ci2) {
            float win[10][3];
            #pragma unroll
            for (int dr = 0; dr < 10; ++dr) {
                const float* sp = &sI[ci2 * 1360 + (g8 + dr) * 40 + cc + 3];
                win[dr][0] = sp[0]; win[dr][1] = sp[1]; win[dr][2] = sp[2];
            }
            const int ci = chunk * 2 + ci2;
            #pragma unroll
            for (int co = 0; co < 4; ++co) {
                const float4* wq = (const float4*)&sW2[(ci * 8 + cq + co) * 12];
                float4 wa = wq[0], wb = wq[1], wc = wq[2];
                #pragma unroll
                for (int p = 0; p < 8; ++p)
                    acc[co][p] += win[p][0]*wa.x + win[p][1]*wa.y + win[p][2]*wa.z
                                + win[p+1][0]*wa.w + win[p+1][1]*wb.x + win[p+1][2]*wb.y
                                + win[p+2][0]*wb.z + win[p+2][1]*wb.w + win[p+2][2]*wc.x;
            }
        }
        __syncthreads();
    }
    // 2x2 maxpool: vertical pairs in-thread, horizontal via shfl_xor(1)
    const bool writer = (cc & 1) == 0;
    #pragma unroll
    for (int co = 0; co < 4; ++co) {
        float b0 = bias[co0 + cq + co];
        float* ob = out + (size_t)bt * 8192 + (co0 + cq + co) * 256;
        #pragma unroll
        for (int i = 0; i < 4; ++i) {
            float v = fmaxf(acc[co][2 * i], acc[co][2 * i + 1]);
            v = fmaxf(v, __shfl_xor(v, 1, 64));
            if (writer) ob[(g8 / 2 + i) * 16 + (cc >> 1)] = v + b0;
        }
    }
}

// conv3 (32->64ch, 3x3 SAME on 16x16). [R15]
__global__ __launch_bounds__(256) void k_conv3(const float* __restrict__ s2,
    const float* __restrict__ w, const float* __restrict__ bias, float* __restrict__ out)
{
    __shared__ float sI[4 * 18 * 24];     // [ci4][r+1][c+4], halo = 0 (6.9KB)
    __shared__ float sW3[4 * 32 * 12];    // [ci4][co32][12] (k 0..8) (6.1KB)
    const int bt = blockIdx.y;
    const int co0 = blockIdx.x * 32;
    const int tid = threadIdx.x;
    for (int i = tid; i < 4 * 18 * 24; i += 256) sI[i] = 0.f;
    const int cc = tid & 15;
    const int g8 = ((tid >> 4) & 1) * 8;
    const int cq = (tid >> 5) * 4;        // local co base 0..28
    float acc[4][8] = {};
    const float* img = s2 + (size_t)bt * 8192;

    float4 pf0;                           // 4ci chunk = 1024 floats = 256 f4
    auto loadStage = [&](int chunk) {
        pf0 = ((const float4*)(img + chunk * 1024))[tid];
    };
    auto writeStage = [&]() {
        int lin = tid * 4;
        int ci = lin >> 8, rc = lin & 255;   // ci 0..3
        int r = rc >> 4, c = rc & 15;
        *(float4*)&sI[ci * 432 + (r + 1) * 24 + (c + 4)] = pf0;
    };

    loadStage(0);
    __syncthreads();
    for (int chunk = 0; chunk < 8; ++chunk) {
        writeStage();
        for (int i = tid; i < 4 * 32 * 9; i += 256) {   // weights 4ci x 32co
            int ci = i / 288, rest = i % 288;
            int co = rest / 9, k = rest % 9;
            sW3[(ci * 32 + co) * 12 + k] = w[((co0 + co) * 32 + chunk * 4 + ci) * 9 + k];
        }
        if (chunk < 7) loadStage(chunk + 1);
        __syncthreads();
        #pragma unroll
        for (int ci4 = 0; ci4 < 4; ++ci4) {
            float win[10][3];
            #pragma unroll
            for (int dr = 0; dr < 10; ++dr) {
                const float* sp = &sI[ci4 * 432 + (g8 + dr) * 24 + cc + 3];
                win[dr][0] = sp[0]; win[dr][1] = sp[1]; win[dr][2] = sp[2];
            }
            #pragma unroll
            for (int co = 0; co < 4; ++co) {
                const float4* wq = (const float4*)&sW3[(ci4 * 32 + cq + co) * 12];
                float4 wa = wq[0], wb = wq[1], wc = wq[2];
                #pragma unroll
                for (int p = 0; p < 8; ++p)
                    acc[co][p] += win[p][0]*wa.x + win[p][1]*wa.y + win[p][2]*wa.z
                                + win[p+1][0]*wa.w + win[p+1][1]*wb.x + win[p+1][2]*wb.y
                                + win[p+2][0]*wb.z + win[p+2][1]*wb.w + win[p+2][2]*wc.x;
            }
        }
        __syncthreads();
    }
    #pragma unroll
    for (int co = 0; co < 4; ++co) {
        float b0 = bias[co0 + cq + co];
        float* ob = out + (size_t)bt * 16384 + (co0 + cq + co) * 256;
        #pragma unroll
        for (int p = 0; p < 8; ++p)
            ob[(g8 + p) * 16 + cc] = acc[co][p] + b0;
    }
}

// LIF3 + rate_smooth fused: ring buffer of last 5 spikes, emit act[t-2]
__global__ __launch_bounds__(256) void k_lif3smooth(const float* __restrict__ cur,
                                                    float* __restrict__ act)
{
    int idx = blockIdx.x * 256 + threadIdx.x;   // B*16384
    int b = idx >> 14, f = idx & 16383;
    const float* cp = cur + (size_t)b * TT * 16384 + f;
    float* ap = act + (size_t)b * TT * 16384 + f;
    float m = 0.f;
    float s0 = 0, s1 = 0, s2 = 0, s3 = 0, s4 = 0;
    for (int t = 0; t < TT + 2; ++t) {
        float s = 0.f;
        if (t < TT) {
            float cv = cp[(size_t)t * 16384];
            float reset = (m > THR) ? THR : 0.f;
            m = BETA * m + cv - reset;
            s = (m > THR) ? 1.f : 0.f;
        }
        s4 = s3; s3 = s2; s2 = s1; s1 = s0; s0 = s;
        if (t >= 2) ap[(size_t)(t - 2) * 16384] = (s0 + s1 + s2 + s3 + s4) * 0.2f;
    }
}

// ---------------- GEMM kernels ----------------

// 64x64 tile, BK=32, split-K, prefetch. High-occupancy; for L2-resident GEMMs.
__global__ __launch_bounds__(256) void k_gemm(const float* __restrict__ A,
    const float* __restrict__ Bm, float* __restrict__ C, int M, int N, int K)
{
    __shared__ float As[32][68];   // transposed A tile: As[k][m]
    __shared__ float Bs[32][68];
    const int tid = threadIdx.x;
    const int n0 = blockIdx.x * 64, m0 = blockIdx.y * 64;
    const int kchunk = K / gridDim.z;
    const int k0 = blockIdx.z * kchunk, k1 = k0 + kchunk;
    const int ar = tid >> 2, ac = (tid & 3) * 8;
    const int br = tid >> 4, bc = (tid & 15) * 4;
    const int row0 = (tid >> 4) * 4, col0 = (tid & 15) * 4;
    float acc[4][4] = {};
    float4 av0 = *(const float4*)&A[(size_t)(m0 + ar) * K + k0 + ac];
    float4 av1 = *(const float4*)&A[(size_t)(m0 + ar) * K + k0 + ac + 4];
    float4 bv0 = *(const float4*)&Bm[(size_t)(k0 + br) * N + n0 + bc];
    float4 bv1 = *(const float4*)&Bm[(size_t)(k0 + br + 16) * N + n0 + bc];
    for (int kk = k0; kk < k1; kk += 32) {
        As[ac + 0][ar] = av0.x; As[ac + 1][ar] = av0.y;
        As[ac + 2][ar] = av0.z; As[ac + 3][ar] = av0.w;
        As[ac + 4][ar] = av1.x; As[ac + 5][ar] = av1.y;
        As[ac + 6][ar] = av1.z; As[ac + 7][ar] = av1.w;
        *(float4*)&Bs[br][bc] = bv0;
        *(float4*)&Bs[br + 16][bc] = bv1;
        __syncthreads();
        if (kk + 32 < k1) {   // prefetch next tile while computing this one
            av0 = *(const float4*)&A[(size_t)(m0 + ar) * K + kk + 32 + ac];
            av1 = *(const float4*)&A[(size_t)(m0 + ar) * K + kk + 32 + ac + 4];
            bv0 = *(const float4*)&Bm[(size_t)(kk + 32 + br) * N + n0 + bc];
            bv1 = *(const float4*)&Bm[(size_t)(kk + 32 + br + 16) * N + n0 + bc];
        }
        #pragma unroll
        for (int k = 0; k < 32; ++k) {
            float4 a4 = *(const float4*)&As[k][row0];
            float4 b4 = *(const float4*)&Bs[k][col0];
            acc[0][0] += a4.x * b4.x; acc[0][1] += a4.x * b4.y; acc[0][2] += a4.x * b4.z; acc[0][3] += a4.x * b4.w;
            acc[1][0] += a4.y * b4.x; acc[1][1] += a4.y * b4.y; acc[1][2] += a4.y * b4.z; acc[1][3] += a4.y * b4.w;
            acc[2][0] += a4.z * b4.x; acc[2][1] += a4.z * b4.y; acc[2][2] += a4.z * b4.z; acc[2][3] += a4.z * b4.w;
            acc[3][0] += a4.w * b4.x; acc[3][1] += a4.w * b4.y; acc[3][2] += a4.w * b4.z; acc[3][3] += a4.w * b4.w;
        }
        __syncthreads();
    }
    float* Cp = C + (size_t)blockIdx.z * M * N;
    #pragma unroll
    for (int i = 0; i < 4; ++i) {
        float4 o;
        o.x = acc[i][0]; o.y = acc[i][1]; o.z = acc[i][2]; o.w = acc[i][3];
        *(float4*)&Cp[(size_t)(m0 + row0 + i) * N + n0 + col0] = o;
    }
}

// 128x128 tile, 8x8 acc, BK=16. Halves HBM re-reads; for the K=16384
// HBM-bound input GEMM ONLY (traffic 528MB -> 264MB).
__global__ __launch_bounds__(256) void k_gemm128(const float* __restrict__ A,
    const float* __restrict__ Bm, float* __restrict__ C, int M, int N, int K)
{
    __shared__ float As[16][132];   // transposed A tile: As[k][m]
    __shared__ float Bs[16][132];
    const int tid = threadIdx.x;
    const int n0 = blockIdx.x * 128, m0 = blockIdx.y * 128;
    const int kchunk = K / gridDim.z;
    const int k0 = blockIdx.z * kchunk, k1 = k0 + kchunk;
    const int ar0 = (tid * 2) >> 2,     ac0 = ((tid * 2) & 3) * 4;
    const int ar1 = (tid * 2 + 1) >> 2, ac1 = ((tid * 2 + 1) & 3) * 4;
    const int br0 = (tid * 2) >> 5,     bc0 = ((tid * 2) & 31) * 4;
    const int br1 = (tid * 2 + 1) >> 5, bc1 = ((tid * 2 + 1) & 31) * 4;
    const int row0 = (tid >> 4) * 8, col0 = (tid & 15) * 8;
    float acc[8][8] = {};
    float4 av0, av1, bv0, bv1;
    auto gload = [&](int kk) {
        av0 = *(const float4*)&A[(size_t)(m0 + ar0) * K + kk + ac0];
        av1 = *(const float4*)&A[(size_t)(m0 + ar1) * K + kk + ac1];
        bv0 = *(const float4*)&Bm[(size_t)(kk + br0) * N + n0 + bc0];
        bv1 = *(const float4*)&Bm[(size_t)(kk + br1) * N + n0 + bc1];
    };
    gload(k0);
    for (int kk = k0; kk < k1; kk += 16) {
        As[ac0 + 0][ar0] = av0.x; As[ac0 + 1][ar0] = av0.y;
        As[ac0 + 2][ar0] = av0.z; As[ac0 + 3][ar0] = av0.w;
        As[ac1 + 0][ar1] = av1.x; As[ac1 + 1][ar1] = av1.y;
        As[ac1 + 2][ar1] = av1.z; As[ac1 + 3][ar1] = av1.w;
        *(float4*)&Bs[br0][bc0] = bv0;
        *(float4*)&Bs[br1][bc1] = bv1;
        __syncthreads();
        if (kk + 16 < k1) gload(kk + 16);   // prefetch overlaps compute
        #pragma unroll
        for (int k = 0; k < 16; ++k) {
            float4 a0 = *(const float4*)&As[k][row0];
            float4 a1 = *(const float4*)&As[k][row0 + 4];
            float4 b0 = *(const float4*)&Bs[k][col0];
            float4 b1 = *(const float4*)&Bs[k][col0 + 4];
            float a[8] = {a0.x, a0.y, a0.z, a0.w, a1.x, a1.y, a1.z, a1.w};
            float b[8] = {b0.x, b0.y, b0.z, b0.w, b1.x, b1.y, b1.z, b1.w};
            #pragma unroll
            for (int i = 0; i < 8; ++i)
                #pragma unroll
                for (int j = 0; j < 8; ++j)
                    acc[i][j] += a[i] * b[j];
        }
        __syncthreads();
    }
    float* Cp = C + (size_t)blockIdx.z * M * N;
    #pragma unroll
    for (int i = 0; i < 8; ++i) {
        float4 o0, o1;
        o0.x = acc[i][0]; o0.y = acc[i][1]; o0.z = acc[i][2]; o0.w = acc[i][3];
        o1.x = acc[i][4]; o1.y = acc[i][5]; o1.z = acc[i][6]; o1.w = acc[i][7];
        *(float4*)&Cp[(size_t)(m0 + row0 + i) * N + n0 + col0] = o0;
        *(float4*)&Cp[(size_t)(m0 + row0 + i) * N + n0 + col0 + 4] = o1;
    }
}

template <bool ADD, bool BIAS>
__global__ __launch_bounds__(256) void k_reduce(const float* __restrict__ part,
    const float* __restrict__ bias, float* __restrict__ out, int MN, int N, int KS)
{
    int i4 = (blockIdx.x * 256 + threadIdx.x) * 4;
    if (i4 >= MN) return;
    float4 v = {0.f, 0.f, 0.f, 0.f};
    for (int z = 0; z < KS; ++z) {
        float4 p = *(const float4*)&part[(size_t)z * MN + i4];
        v.x += p.x; v.y += p.y; v.z += p.z; v.w += p.w;
    }
    if (BIAS) {
        float4 bv = *(const float4*)&bias[i4 % N];
        v.x += bv.x; v.y += bv.y; v.z += bv.z; v.w += bv.w;
    }
    if (ADD) {
        float4 o = *(const float4*)&out[i4];
        v.x += o.x; v.y += o.y; v.z += o.z; v.w += o.w;
    }
    *(float4*)&out[i4] = v;
}

// ---------------- mamba pieces ----------------

__device__ __forceinline__ float blockSum(float v, float* red)
{
    #pragma unroll
    for (int o = 32; o; o >>= 1) v += __shfl_down(v, o, 64);
    const int wv = threadIdx.x >> 6, lane = threadIdx.x & 63;
    if (lane == 0) red[wv] = v;
    __syncthreads();
    float r = red[0] + red[1] + red[2] + red[3];
    __syncthreads();
    return r;
}

__global__ __launch_bounds__(256) void k_ln(const float* __restrict__ x,
    const float* __restrict__ w, const float* __restrict__ b, float* __restrict__ out)
{
    __shared__ float red[4];
    int row = blockIdx.x;
    const float* xp = x + (size_t)row * 512;
    int c = threadIdx.x * 2;
    float2 v = *(const float2*)&xp[c];
    float mu = blockSum(v.x + v.y, red) * (1.f / 512.f);
    float d0 = v.x - mu, d1 = v.y - mu;
    float var = blockSum(d0 * d0 + d1 * d1, red) * (1.f / 512.f);
    float inv = rsqrtf(var + 1e-5f);
    float2 o;
    o.x = d0 * inv * w[c] + b[c];
    o.y = d1 * inv * w[c + 1] + b[c + 1];
    *(float2*)&out[(size_t)row * 512 + c] = o;
}

// causal depthwise conv (D_CONV=4) + silu
__global__ __launch_bounds__(256) void k_convsilu(const float* __restrict__ xr,
    const float* __restrict__ cw, float* __restrict__ xc)
{
    int idx = blockIdx.x * 256 + threadIdx.x;   // B*T*1024
    int row = idx >> 10;
    int d = idx & 1023;
    int t = row & 63;
    const float* xi = xr + (size_t)(row - t) * 2048 + d;
    float4 w = *(const float4*)&cw[d * 4];
    float a = w.w * xi[(size_t)t * 2048];
    if (t >= 1) a += w.z * xi[(size_t)(t - 1) * 2048];
    if (t >= 2) a += w.y * xi[(size_t)(t - 2) * 2048];
    if (t >= 3) a += w.x * xi[(size_t)(t - 3) * 2048];
    xc[idx] = a / (1.f + __expf(-a));
}

// skinny GEMM: xdbl = xc @ xproj_w  (M=512, K=1024, N=64)
__global__ __launch_bounds__(64) void k_xproj(const float* __restrict__ xc,
    const float* __restrict__ w, float* __restrict__ xdbl)
{
    int row = blockIdx.x;
    int col = threadIdx.x;
    const float* a = xc + (size_t)row * 1024;
    float acc = 0.f;
    #pragma unroll 4
    for (int k = 0; k < 1024; k += 4) {
        float4 av = *(const float4*)&a[k];
        acc += av.x * w[(size_t)k * 64 + col] + av.y * w[(size_t)(k + 1) * 64 + col]
             + av.z * w[(size_t)(k + 2) * 64 + col] + av.w * w[(size_t)(k + 3) * 64 + col];
    }
    xdbl[(size_t)row * 64 + col] = acc;
}

// dt = softplus(xdbl[:, :32] @ dt_w + dt_b)
__global__ __launch_bounds__(256) void k_dtproj(const float* __restrict__ xdbl,
    const float* __restrict__ w, const float* __restrict__ bias, float* __restrict__ dt)
{
    int idx = blockIdx.x * 256 + threadIdx.x;   // 512*1024
    int row = idx >> 10, d = idx & 1023;
    const float* a = xdbl + (size_t)row * 64;
    float acc = bias[d];
    #pragma unroll 8
    for (int r = 0; r < 32; ++r) acc += a[r] * w[(size_t)r * 1024 + d];
    dt[idx] = fmaxf(acc, 0.f) + log1pf(__expf(-fabsf(acc)));
}

// selective scan, fused with +xc*Dp and *silu(res).
__global__ __launch_bounds__(64) void k_scan(const float* __restrict__ dt,
    const float* __restrict__ xc, const float* __restrict__ xdbl,
    const float* __restrict__ xr, const float* __restrict__ A_log,
    const float* __restrict__ Dp, float* __restrict__ y)
{
    const int lane = threadIdx.x & 63;
    const int half = lane >> 5;                       // 0: n=0..7, 1: n=8..15
    const int p = blockIdx.x * 32 + (lane & 31);      // pair id, 8192 total
    const int b = p >> 10, d = p & 1023;
    float A[8];
    #pragma unroll
    for (int n = 0; n < 8; ++n) A[n] = -__expf(A_log[d * 16 + half * 8 + n]);
    float Dv = Dp[d];
    float h[8] = {};
    const int row0 = b * 64;
    size_t base = (size_t)row0 * 1024 + d;
    float dtv = dt[base], xv = xc[base];
    float res = xr[(size_t)row0 * 2048 + 1024 + d];
    const float4* Bp = (const float4*)&xdbl[(size_t)row0 * 64 + 32 + half * 8];
    const float4* Cq = (const float4*)&xdbl[(size_t)row0 * 64 + 48 + half * 8];
    float4 B0 = Bp[0], B1 = Bp[1];
    float4 C0 = Cq[0], C1 = Cq[1];
    for (int t = 0; t < TT; ++t) {
        float dtv_n = 0.f, xv_n = 0.f, res_n = 0.f;
        float4 B0n = {}, B1n = {}, C0n = {}, C1n = {};
        if (t < TT - 1) {
            size_t b2 = base + (size_t)(t + 1) * 1024;
            dtv_n = dt[b2]; xv_n = xc[b2];
            res_n = xr[(size_t)(row0 + t + 1) * 2048 + 1024 + d];
            const float4* Bp2 = (const float4*)&xdbl[(size_t)(row0 + t + 1) * 64 + 32 + half * 8];
            const float4* Cq2 = (const float4*)&xdbl[(size_t)(row0 + t + 1) * 64 + 48 + half * 8];
            B0n = Bp2[0]; B1n = Bp2[1]; C0n = Cq2[0]; C1n = Cq2[1];
        }
        float dtx = dtv * xv;
        float acch = 0.f;
        #define SCAN_STEP(Bv, Cv, n0)                                             \
        {                                                                         \
            float bb[4] = {Bv.x, Bv.y, Bv.z, Bv.w};                               \
            float cv[4] = {Cv.x, Cv.y, Cv.z, Cv.w};                               \
            _Pragma("unroll")                                                     \
            for (int r = 0; r < 4; ++r) {                                         \
                int n = n0 + r;                                                   \
                float hv = __expf(dtv * A[n]) * h[n] + dtx * bb[r];               \
                h[n] = hv;                                                        \
                acch += hv * cv[r];                                               \
            }                                                                     \
        }
        SCAN_STEP(B0, C0, 0) SCAN_STEP(B1, C1, 4)
        #undef SCAN_STEP
        float acc = acch + __shfl_xor(acch, 32, 64);
        float sil = res / (1.f + __expf(-res));
        if (half == 0)
            y[(size_t)(row0 + t) * 1024 + d] = (acc + xv * Dv) * sil;
        dtv = dtv_n; xv = xv_n; res = res_n;
        B0 = B0n; B1 = B1n; C0 = C0n; C1 = C1n;
    }
}

__global__ __launch_bounds__(256) void k_meant(const float* __restrict__ h,
                                               float* __restrict__ hm)
{
    int idx = blockIdx.x * 256 + threadIdx.x;   // 8*512
    int b = idx >> 9, d = idx & 511;
    const float* p = h + (size_t)b * 64 * 512 + d;
    float s = 0.f;
    for (int t = 0; t < 64; ++t) s += p[t * 512];
    hm[idx] = s * (1.f / 64.f);
}

__global__ __launch_bounds__(256) void k_final(const float* __restrict__ hm,
    const float* __restrict__ fw, const float* __restrict__ fb,
    const float* __restrict__ cw, const float* __restrict__ cb, float* __restrict__ out)
{
    __shared__ float red[4];
    __shared__ float nrm[512];
    int b = blockIdx.x;
    const float* xp = hm + (size_t)b * 512;
    int c2 = threadIdx.x * 2;
    float2 v = *(const float2*)&xp[c2];
    float mu = blockSum(v.x + v.y, red) * (1.f / 512.f);
    float d0 = v.x - mu, d1 = v.y - mu;
    float var = blockSum(d0 * d0 + d1 * d1, red) * (1.f / 512.f);
    float inv = rsqrtf(var + 1e-5f);
    nrm[c2] = d0 * inv * fw[c2] + fb[c2];
    nrm[c2 + 1] = d1 * inv * fw[c2 + 1] + fb[c2 + 1];
    __syncthreads();
    for (int c = 0; c < 11; ++c) {
        float p = nrm[threadIdx.x] * cw[threadIdx.x * 11 + c]
                + nrm[threadIdx.x + 256] * cw[(threadIdx.x + 256) * 11 + c];
        float s = blockSum(p, red);
        if (threadIdx.x == 0) out[b * 11 + c] = s + cb[c];
    }
}

// ---------------- host ----------------

extern "C" void kernel_launch(void* const* d_in, const int* in_sizes, int n_in,
                              void* d_out, int out_size, void* d_ws, size_t ws_size,
                              hipStream_t stream)
{
    const float* x      = (const float*)d_in[0];
    const float* c1w    = (const float*)d_in[1];
    const float* c1b    = (const float*)d_in[2];
    const float* c2w    = (const float*)d_in[3];
    const float* c2b    = (const float*)d_in[4];
    const float* c3w    = (const float*)d_in[5];
    const float* c3b    = (const float*)d_in[6];
    const float* inp_w  = (const float*)d_in[7];
    const float* inp_b  = (const float*)d_in[8];
    const float* ln_w   = (const float*)d_in[9];
    const float* ln_b   = (const float*)d_in[10];
    const float* in_w   = (const float*)d_in[11];
    const float* conv_w = (const float*)d_in[12];
    const float* xproj_w= (const float*)d_in[13];
    const float* dt_w   = (const float*)d_in[14];
    const float* dt_b   = (const float*)d_in[15];
    const float* A_log  = (const float*)d_in[16];
    const float* Dp     = (const float*)d_in[17];
    const float* mb_out_w=(const float*)d_in[18];
    const float* fn_w   = (const float*)d_in[19];
    const float* fn_b   = (const float*)d_in[20];
    const float* cls_w  = (const float*)d_in[21];
    const float* cls_b  = (const float*)d_in[22];
    float* out = (float*)d_out;

    float* ws   = (float*)d_ws;
    float* bufA = ws;                       // 16,777,216 floats (67 MB)
    float* bufB = bufA + 16777216;          // 16,777,216
    float* h    = bufB + 16777216;          // 262,144
    float* hn   = h    + 262144;            // 262,144
    float* xr   = hn   + 262144;            // 1,048,576
    float* xc   = xr   + 1048576;           // 524,288
    float* xdbl = xc   + 524288;            // 32,768
    float* dtb  = xdbl + 32768;             // 524,288
    float* yb   = dtb  + 524288;            // 524,288
    float* hm   = yb   + 524288;            // 4,096

    // frontend
    k_conv1pool<<<512, 256, 0, stream>>>(x, c1w, c1b, bufA);
    k_lif<<<1024, 256, 0, stream>>>(bufA, bufB, 32768);               // -> s1
    k_conv2<<<dim3(4, 512), 256, 0, stream>>>(bufB, c2w, c2b, bufA);  // pooled cur2
    k_lif<<<256, 256, 0, stream>>>(bufA, bufB, 8192);                 // -> s2
    k_conv3<<<dim3(2, 512), 256, 0, stream>>>(bufB, c3w, c3b, bufA);  // cur3
    k_lif3smooth<<<512, 256, 0, stream>>>(bufA, bufB);                // -> act

    // input projection: act(512x16384) @ inp_w(16384x512), split-K=32
    // 128x128 tile kernel: HBM traffic 528MB -> 264MB on this K=16384 GEMM
    k_gemm128<<<dim3(4, 4, 32), 256, 0, stream>>>(bufB, inp_w, bufA, 512, 512, 16384);
    k_reduce<false, true><<<256, 256, 0, stream>>>(bufA, inp_b, h, 262144, 512, 32);

    for (int l = 0; l < 4; ++l) {
        k_ln<<<512, 256, 0, stream>>>(h, ln_w + l * 512, ln_b + l * 512, hn);
        k_gemm<<<dim3(32, 8, 4), 256, 0, stream>>>(hn, in_w + (size_t)l * 1048576, bufA, 512, 2048, 512);
        k_reduce<false, false><<<1024, 256, 0, stream>>>(bufA, nullptr, xr, 1048576, 2048, 4);
        k_convsilu<<<2048, 256, 0, stream>>>(xr, conv_w + l * 4096, xc);
        k_xproj<<<512, 64, 0, stream>>>(xc, xproj_w + l * 65536, xdbl);
        k_dtproj<<<2048, 256, 0, stream>>>(xdbl, dt_w + l * 32768, dt_b + l * 1024, dtb);
        k_scan<<<256, 64, 0, stream>>>(dtb, xc, xdbl, xr, A_log + l * 16384, Dp + l * 1024, yb);
        k_gemm<<<dim3(8, 8, 16), 256, 0, stream>>>(yb, mb_out_w + (size_t)l * 524288, bufA, 512, 512, 1024);
        k_reduce<true, false><<<256, 256, 0, stream>>>(bufA, nullptr, h, 262144, 512, 16);
    }

    k_meant<<<16, 256, 0, stream>>>(h, hm);
    k_final<<<8, 256, 0, stream>>>(hm, fn_w, fn_b, cls_w, cls_b, out);
}

// Round 19
// 927.702 us; speedup vs baseline: 1.0047x; 1.0047x over previous
//
#include <hip/hip_runtime.h>
#include <math.h>

// ---------------------------------------------------------------------------
// MambaSpike forward: SNN conv frontend + rate smoothing + 4 mamba blocks.
// All fp32. LIF membrane scans are the ONLY sequential-in-T parts and are
// elementwise; convs/GEMMs are batched over B*T=512.
// R19 (FINAL): exact R15/R17 state, best measured 927.9/928.0us.
// R18's 128-tile input GEMM was null: act+inp_w fit in 256MB L3, so the
// presumed HBM re-reads were L3 hits (FETCH_SIZE gotcha). 64x64/BK=32
// high-occupancy GEMM wins everywhere on these shapes.
// Journey: 1337 (R1 first correct) -> 928 via: split-K+prefetch GEMM,
// conv window-hoist, bank-conflict-free lane mappings, weights-in-LDS
// b128 quads, VGPR<128 occupancy diets (conv2 124 VGPR), all-CU grids.
// ---------------------------------------------------------------------------

static constexpr int TT = 64;
static constexpr float BETA = 0.9f, THR = 1.0f;

// ---------------- frontend ----------------

// conv1 (2->32ch, 3x3 SAME on 64x64) + 2x2 maxpool, fused. Block per (b,t).
__global__ __launch_bounds__(256) void k_conv1pool(const float* __restrict__ x,
    const float* __restrict__ w, const float* __restrict__ bias, float* __restrict__ out)
{
    __shared__ float sI[2 * 66 * 76];   // [ci][row+1][col+4], halo = 0
    __shared__ float sW[576];
    const int bt = blockIdx.x;
    const int tid = threadIdx.x;
    for (int i = tid; i < 2 * 66 * 76; i += 256) sI[i] = 0.f;
    for (int i = tid; i < 576; i += 256) sW[i] = w[i];
    __syncthreads();
    const float* img = x + (size_t)bt * 8192;
    for (int i = tid; i < 2048; i += 256) {
        float4 v4 = ((const float4*)img)[i];
        int lin = i * 4;
        int ci = lin >> 12, rc = lin & 4095;
        int r = rc >> 6, c = rc & 63;
        *(float4*)&sI[ci * 5016 + (r + 1) * 76 + (c + 4)] = v4;
    }
    __syncthreads();
    const int oh = tid >> 3;           // pooled row 0..31
    const int p8 = (tid & 7) * 8;
    float v[2][4][10];
    #pragma unroll
    for (int ci = 0; ci < 2; ++ci) {
        #pragma unroll
        for (int dr = 0; dr < 4; ++dr) {
            const float* rp = &sI[ci * 5016 + (2 * oh + dr) * 76 + p8];
            float2 a  = *(const float2*)&rp[2];
            float4 b4 = *(const float4*)&rp[4];
            float4 c4 = *(const float4*)&rp[8];
            float2 e  = *(const float2*)&rp[12];
            v[ci][dr][0] = a.y;
            v[ci][dr][1] = b4.x; v[ci][dr][2] = b4.y; v[ci][dr][3] = b4.z; v[ci][dr][4] = b4.w;
            v[ci][dr][5] = c4.x; v[ci][dr][6] = c4.y; v[ci][dr][7] = c4.z; v[ci][dr][8] = c4.w;
            v[ci][dr][9] = e.x;
        }
    }
    const int ow0 = (tid & 7) * 4;
    float* obase = out + (size_t)bt * 32768;
    for (int co = 0; co < 32; ++co) {
        float pos[2][8];
        #pragma unroll
        for (int i = 0; i < 2; ++i)
            #pragma unroll
            for (int j = 0; j < 8; ++j) pos[i][j] = 0.f;
        #pragma unroll
        for (int ci = 0; ci < 2; ++ci) {
            const float* wp = &sW[(co * 2 + ci) * 9];
            float w0=wp[0],w1=wp[1],w2=wp[2],w3=wp[3],w4=wp[4],w5=wp[5],w6=wp[6],w7=wp[7],w8=wp[8];
            #pragma unroll
            for (int pr = 0; pr < 2; ++pr)
                #pragma unroll
                for (int pc = 0; pc < 8; ++pc)
                    pos[pr][pc] += v[ci][pr][pc]*w0 + v[ci][pr][pc+1]*w1 + v[ci][pr][pc+2]*w2
                                 + v[ci][pr+1][pc]*w3 + v[ci][pr+1][pc+1]*w4 + v[ci][pr+1][pc+2]*w5
                                 + v[ci][pr+2][pc]*w6 + v[ci][pr+2][pc+1]*w7 + v[ci][pr+2][pc+2]*w8;
        }
        float b0 = bias[co];
        float4 o;
        o.x = fmaxf(fmaxf(pos[0][0], pos[0][1]), fmaxf(pos[1][0], pos[1][1])) + b0;
        o.y = fmaxf(fmaxf(pos[0][2], pos[0][3]), fmaxf(pos[1][2], pos[1][3])) + b0;
        o.z = fmaxf(fmaxf(pos[0][4], pos[0][5]), fmaxf(pos[1][4], pos[1][5])) + b0;
        o.w = fmaxf(fmaxf(pos[0][6], pos[0][7]), fmaxf(pos[1][6], pos[1][7])) + b0;
        *(float4*)&obase[co * 1024 + oh * 32 + ow0] = o;
    }
}

// generic LIF scan: thread per (b, chw) position, loop t.  spk = (m>THR)
__global__ __launch_bounds__(256) void k_lif(const float* __restrict__ cur,
                                             float* __restrict__ spk, int chw)
{
    int idx = blockIdx.x * 256 + threadIdx.x;
    int b = idx / chw, p = idx % chw;
    const float* cp = cur + (size_t)b * TT * chw + p;
    float* sp = spk + (size_t)b * TT * chw + p;
    float m = 0.f;
    for (int t = 0; t < TT; ++t) {
        float c = cp[(size_t)t * chw];
        float reset = (m > THR) ? THR : 0.f;
        m = BETA * m + c - reset;
        sp[(size_t)t * chw] = (m > THR) ? 1.f : 0.f;
    }
}

// conv2 (32->32ch, 3x3 SAME on 32x32) + fused 2x2 maxpool + bias.
// Thread: 8 consecutive rows x 1 col x 4 co. Grid: (co-group 4, image 512).
// 2ci chunks (16 iters), 2x f4 prefetch -> VGPR 124 (<128 bucket), occ 21%.
__global__ __launch_bounds__(256) void k_conv2(const float* __restrict__ s1,
    const float* __restrict__ w, const float* __restrict__ bias, float* __restrict__ out)
{
    __shared__ float sI[2 * 34 * 40];   // [ci2][r+1][c+4], halo = 0 (10.9KB)
    __shared__ float sW2[32 * 8 * 12];  // [ci32][co8][12] (k 0..8 used)
    const int bt = blockIdx.y;
    const int co0 = blockIdx.x * 8;
    const int tid = threadIdx.x;
    for (int i = tid; i < 2 * 34 * 40; i += 256) sI[i] = 0.f;
    for (int i = tid; i < 2304; i += 256) {       // all weights upfront
        int ci = i / 72, rest = i % 72;
        int co = rest / 9, k = rest % 9;
        sW2[(ci * 8 + co) * 12 + k] = w[((co0 + co) * 32 + ci) * 9 + k];
    }
    const int cc = tid & 31;
    const int g8 = ((tid >> 5) & 3) * 8;    // row base 0,8,16,24
    const int cq = (tid >> 7) * 4;          // local co base 0 or 4
    float acc[4][8] = {};
    const float* img = s1 + (size_t)bt * 32768;

    float4 pf0, pf1;                        // 2ci chunk = 512 f4
    auto loadStage = [&](int chunk) {
        const float4* src = (const float4*)(img + chunk * 2048);
        pf0 = src[tid]; pf1 = src[tid + 256];
    };
    auto writeStage = [&]() {
        #pragma unroll
        for (int j = 0; j < 2; ++j) {
            float4 v4 = j ? pf1 : pf0;
            int lin = (tid + j * 256) * 4;
            int ci = lin >> 10, rc = lin & 1023;   // ci 0..1
            int r = rc >> 5, c = rc & 31;
            *(float4*)&sI[ci * 1360 + (r + 1) * 40 + (c + 4)] = v4;
        }
    };

    loadStage(0);
    __syncthreads();            // zero-init + weight stage complete
    for (int chunk = 0; chunk < 16; ++chunk) {
        writeStage();
        if (chunk < 15) loadStage(chunk + 1);   // overlaps compute below
        __syncthreads();
        #pragma unroll
        for (int ci2 = 0; ci2 < 2; ++ci2) {
            float win[10][3];
            #pragma unroll
            for (int dr = 0; dr < 10; ++dr) {
                const float* sp = &sI[ci2 * 1360 + (g8 + dr) * 40 + cc + 3];
                win[dr][0] = sp[0]; win[dr][1] = sp[1]; win[dr][2] = sp[2];
            }
            const int ci = chunk * 2 + ci2;
            #pragma unroll
            for (int co = 0; co < 4; ++co) {
                const float4* wq = (const float4*)&sW2[(ci * 8 + cq + co) * 12];
                float4 wa = wq[0], wb = wq[1], wc = wq[2];
                #pragma unroll
                for (int p = 0; p < 8; ++p)
                    acc[co][p] += win[p][0]*wa.x + win[p][1]*wa.y + win[p][2]*wa.z
                                + win[p+1][0]*wa.w + win[p+1][1]*wb.x + win[p+1][2]*wb.y
                                + win[p+2][0]*wb.z + win[p+2][1]*wb.w + win[p+2][2]*wc.x;
            }
        }
        __syncthreads();
    }
    // 2x2 maxpool: vertical pairs in-thread, horizontal via shfl_xor(1)
    const bool writer = (cc & 1) == 0;
    #pragma unroll
    for (int co = 0; co < 4; ++co) {
        float b0 = bias[co0 + cq + co];
        float* ob = out + (size_t)bt * 8192 + (co0 + cq + co) * 256;
        #pragma unroll
        for (int i = 0; i < 4; ++i) {
            float v = fmaxf(acc[co][2 * i], acc[co][2 * i + 1]);
            v = fmaxf(v, __shfl_xor(v, 1, 64));
            if (writer) ob[(g8 / 2 + i) * 16 + (cc >> 1)] = v + b0;
        }
    }
}

// conv3 (32->64ch, 3x3 SAME on 16x16). Thread: 8 rows x 1 col x 4 co.
// Grid: (co-group 2, image 512). 4ci chunks (8 iters), 1x f4 prefetch.
__global__ __launch_bounds__(256) void k_conv3(const float* __restrict__ s2,
    const float* __restrict__ w, const float* __restrict__ bias, float* __restrict__ out)
{
    __shared__ float sI[4 * 18 * 24];     // [ci4][r+1][c+4], halo = 0 (6.9KB)
    __shared__ float sW3[4 * 32 * 12];    // [ci4][co32][12] (k 0..8) (6.1KB)
    const int bt = blockIdx.y;
    const int co0 = blockIdx.x * 32;
    const int tid = threadIdx.x;
    for (int i = tid; i < 4 * 18 * 24; i += 256) sI[i] = 0.f;
    const int cc = tid & 15;
    const int g8 = ((tid >> 4) & 1) * 8;
    const int cq = (tid >> 5) * 4;        // local co base 0..28
    float acc[4][8] = {};
    const float* img = s2 + (size_t)bt * 8192;

    float4 pf0;                           // 4ci chunk = 1024 floats = 256 f4
    auto loadStage = [&](int chunk) {
        pf0 = ((const float4*)(img + chunk * 1024))[tid];
    };
    auto writeStage = [&]() {
        int lin = tid * 4;
        int ci = lin >> 8, rc = lin & 255;   // ci 0..3
        int r = rc >> 4, c = rc & 15;
        *(float4*)&sI[ci * 432 + (r + 1) * 24 + (c + 4)] = pf0;
    };

    loadStage(0);
    __syncthreads();
    for (int chunk = 0; chunk < 8; ++chunk) {
        writeStage();
        for (int i = tid; i < 4 * 32 * 9; i += 256) {   // weights 4ci x 32co
            int ci = i / 288, rest = i % 288;
            int co = rest / 9, k = rest % 9;
            sW3[(ci * 32 + co) * 12 + k] = w[((co0 + co) * 32 + chunk * 4 + ci) * 9 + k];
        }
        if (chunk < 7) loadStage(chunk + 1);
        __syncthreads();
        #pragma unroll
        for (int ci4 = 0; ci4 < 4; ++ci4) {
            float win[10][3];
            #pragma unroll
            for (int dr = 0; dr < 10; ++dr) {
                const float* sp = &sI[ci4 * 432 + (g8 + dr) * 24 + cc + 3];
                win[dr][0] = sp[0]; win[dr][1] = sp[1]; win[dr][2] = sp[2];
            }
            #pragma unroll
            for (int co = 0; co < 4; ++co) {
                const float4* wq = (const float4*)&sW3[(ci4 * 32 + cq + co) * 12];
                float4 wa = wq[0], wb = wq[1], wc = wq[2];
                #pragma unroll
                for (int p = 0; p < 8; ++p)
                    acc[co][p] += win[p][0]*wa.x + win[p][1]*wa.y + win[p][2]*wa.z
                                + win[p+1][0]*wa.w + win[p+1][1]*wb.x + win[p+1][2]*wb.y
                                + win[p+2][0]*wb.z + win[p+2][1]*wb.w + win[p+2][2]*wc.x;
            }
        }
        __syncthreads();
    }
    #pragma unroll
    for (int co = 0; co < 4; ++co) {
        float b0 = bias[co0 + cq + co];
        float* ob = out + (size_t)bt * 16384 + (co0 + cq + co) * 256;
        #pragma unroll
        for (int p = 0; p < 8; ++p)
            ob[(g8 + p) * 16 + cc] = acc[co][p] + b0;
    }
}

// LIF3 + rate_smooth fused: ring buffer of last 5 spikes, emit act[t-2]
__global__ __launch_bounds__(256) void k_lif3smooth(const float* __restrict__ cur,
                                                    float* __restrict__ act)
{
    int idx = blockIdx.x * 256 + threadIdx.x;   // B*16384
    int b = idx >> 14, f = idx & 16383;
    const float* cp = cur + (size_t)b * TT * 16384 + f;
    float* ap = act + (size_t)b * TT * 16384 + f;
    float m = 0.f;
    float s0 = 0, s1 = 0, s2 = 0, s3 = 0, s4 = 0;
    for (int t = 0; t < TT + 2; ++t) {
        float s = 0.f;
        if (t < TT) {
            float cv = cp[(size_t)t * 16384];
            float reset = (m > THR) ? THR : 0.f;
            m = BETA * m + cv - reset;
            s = (m > THR) ? 1.f : 0.f;
        }
        s4 = s3; s3 = s2; s2 = s1; s1 = s0; s0 = s;
        if (t >= 2) ap[(size_t)(t - 2) * 16384] = (s0 + s1 + s2 + s3 + s4) * 0.2f;
    }
}

// ---------------- GEMM (fp32, 64x64 tile, BK=32, split-K, prefetch) --------

__global__ __launch_bounds__(256) void k_gemm(const float* __restrict__ A,
    const float* __restrict__ Bm, float* __restrict__ C, int M, int N, int K)
{
    __shared__ float As[32][68];   // transposed A tile: As[k][m]
    __shared__ float Bs[32][68];
    const int tid = threadIdx.x;
    const int n0 = blockIdx.x * 64, m0 = blockIdx.y * 64;
    const int kchunk = K / gridDim.z;
    const int k0 = blockIdx.z * kchunk, k1 = k0 + kchunk;
    const int ar = tid >> 2, ac = (tid & 3) * 8;
    const int br = tid >> 4, bc = (tid & 15) * 4;
    const int row0 = (tid >> 4) * 4, col0 = (tid & 15) * 4;
    float acc[4][4] = {};
    float4 av0 = *(const float4*)&A[(size_t)(m0 + ar) * K + k0 + ac];
    float4 av1 = *(const float4*)&A[(size_t)(m0 + ar) * K + k0 + ac + 4];
    float4 bv0 = *(const float4*)&Bm[(size_t)(k0 + br) * N + n0 + bc];
    float4 bv1 = *(const float4*)&Bm[(size_t)(k0 + br + 16) * N + n0 + bc];
    for (int kk = k0; kk < k1; kk += 32) {
        As[ac + 0][ar] = av0.x; As[ac + 1][ar] = av0.y;
        As[ac + 2][ar] = av0.z; As[ac + 3][ar] = av0.w;
        As[ac + 4][ar] = av1.x; As[ac + 5][ar] = av1.y;
        As[ac + 6][ar] = av1.z; As[ac + 7][ar] = av1.w;
        *(float4*)&Bs[br][bc] = bv0;
        *(float4*)&Bs[br + 16][bc] = bv1;
        __syncthreads();
        if (kk + 32 < k1) {   // prefetch next tile while computing this one
            av0 = *(const float4*)&A[(size_t)(m0 + ar) * K + kk + 32 + ac];
            av1 = *(const float4*)&A[(size_t)(m0 + ar) * K + kk + 32 + ac + 4];
            bv0 = *(const float4*)&Bm[(size_t)(kk + 32 + br) * N + n0 + bc];
            bv1 = *(const float4*)&Bm[(size_t)(kk + 32 + br + 16) * N + n0 + bc];
        }
        #pragma unroll
        for (int k = 0; k < 32; ++k) {
            float4 a4 = *(const float4*)&As[k][row0];
            float4 b4 = *(const float4*)&Bs[k][col0];
            acc[0][0] += a4.x * b4.x; acc[0][1] += a4.x * b4.y; acc[0][2] += a4.x * b4.z; acc[0][3] += a4.x * b4.w;
            acc[1][0] += a4.y * b4.x; acc[1][1] += a4.y * b4.y; acc[1][2] += a4.y * b4.z; acc[1][3] += a4.y * b4.w;
            acc[2][0] += a4.z * b4.x; acc[2][1] += a4.z * b4.y; acc[2][2] += a4.z * b4.z; acc[2][3] += a4.z * b4.w;
            acc[3][0] += a4.w * b4.x; acc[3][1] += a4.w * b4.y; acc[3][2] += a4.w * b4.z; acc[3][3] += a4.w * b4.w;
        }
        __syncthreads();
    }
    float* Cp = C + (size_t)blockIdx.z * M * N;
    #pragma unroll
    for (int i = 0; i < 4; ++i) {
        float4 o;
        o.x = acc[i][0]; o.y = acc[i][1]; o.z = acc[i][2]; o.w = acc[i][3];
        *(float4*)&Cp[(size_t)(m0 + row0 + i) * N + n0 + col0] = o;
    }
}

template <bool ADD, bool BIAS>
__global__ __launch_bounds__(256) void k_reduce(const float* __restrict__ part,
    const float* __restrict__ bias, float* __restrict__ out, int MN, int N, int KS)
{
    int i4 = (blockIdx.x * 256 + threadIdx.x) * 4;
    if (i4 >= MN) return;
    float4 v = {0.f, 0.f, 0.f, 0.f};
    for (int z = 0; z < KS; ++z) {
        float4 p = *(const float4*)&part[(size_t)z * MN + i4];
        v.x += p.x; v.y += p.y; v.z += p.z; v.w += p.w;
    }
    if (BIAS) {
        float4 bv = *(const float4*)&bias[i4 % N];
        v.x += bv.x; v.y += bv.y; v.z += bv.z; v.w += bv.w;
    }
    if (ADD) {
        float4 o = *(const float4*)&out[i4];
        v.x += o.x; v.y += o.y; v.z += o.z; v.w += o.w;
    }
    *(float4*)&out[i4] = v;
}

// ---------------- mamba pieces ----------------

__device__ __forceinline__ float blockSum(float v, float* red)
{
    #pragma unroll
    for (int o = 32; o; o >>= 1) v += __shfl_down(v, o, 64);
    const int wv = threadIdx.x >> 6, lane = threadIdx.x & 63;
    if (lane == 0) red[wv] = v;
    __syncthreads();
    float r = red[0] + red[1] + red[2] + red[3];
    __syncthreads();
    return r;
}

__global__ __launch_bounds__(256) void k_ln(const float* __restrict__ x,
    const float* __restrict__ w, const float* __restrict__ b, float* __restrict__ out)
{
    __shared__ float red[4];
    int row = blockIdx.x;
    const float* xp = x + (size_t)row * 512;
    int c = threadIdx.x * 2;
    float2 v = *(const float2*)&xp[c];
    float mu = blockSum(v.x + v.y, red) * (1.f / 512.f);
    float d0 = v.x - mu, d1 = v.y - mu;
    float var = blockSum(d0 * d0 + d1 * d1, red) * (1.f / 512.f);
    float inv = rsqrtf(var + 1e-5f);
    float2 o;
    o.x = d0 * inv * w[c] + b[c];
    o.y = d1 * inv * w[c + 1] + b[c + 1];
    *(float2*)&out[(size_t)row * 512 + c] = o;
}

// causal depthwise conv (D_CONV=4) + silu
__global__ __launch_bounds__(256) void k_convsilu(const float* __restrict__ xr,
    const float* __restrict__ cw, float* __restrict__ xc)
{
    int idx = blockIdx.x * 256 + threadIdx.x;   // B*T*1024
    int row = idx >> 10;
    int d = idx & 1023;
    int t = row & 63;
    const float* xi = xr + (size_t)(row - t) * 2048 + d;
    float4 w = *(const float4*)&cw[d * 4];
    float a = w.w * xi[(size_t)t * 2048];
    if (t >= 1) a += w.z * xi[(size_t)(t - 1) * 2048];
    if (t >= 2) a += w.y * xi[(size_t)(t - 2) * 2048];
    if (t >= 3) a += w.x * xi[(size_t)(t - 3) * 2048];
    xc[idx] = a / (1.f + __expf(-a));
}

// skinny GEMM: xdbl = xc @ xproj_w  (M=512, K=1024, N=64)
// One row per 64-thread block: 512 blocks cover all 256 CUs.
__global__ __launch_bounds__(64) void k_xproj(const float* __restrict__ xc,
    const float* __restrict__ w, float* __restrict__ xdbl)
{
    int row = blockIdx.x;
    int col = threadIdx.x;
    const float* a = xc + (size_t)row * 1024;
    float acc = 0.f;
    #pragma unroll 4
    for (int k = 0; k < 1024; k += 4) {
        float4 av = *(const float4*)&a[k];
        acc += av.x * w[(size_t)k * 64 + col] + av.y * w[(size_t)(k + 1) * 64 + col]
             + av.z * w[(size_t)(k + 2) * 64 + col] + av.w * w[(size_t)(k + 3) * 64 + col];
    }
    xdbl[(size_t)row * 64 + col] = acc;
}

// dt = softplus(xdbl[:, :32] @ dt_w + dt_b)
__global__ __launch_bounds__(256) void k_dtproj(const float* __restrict__ xdbl,
    const float* __restrict__ w, const float* __restrict__ bias, float* __restrict__ dt)
{
    int idx = blockIdx.x * 256 + threadIdx.x;   // 512*1024
    int row = idx >> 10, d = idx & 1023;
    const float* a = xdbl + (size_t)row * 64;
    float acc = bias[d];
    #pragma unroll 8
    for (int r = 0; r < 32; ++r) acc += a[r] * w[(size_t)r * 1024 + d];
    dt[idx] = fmaxf(acc, 0.f) + log1pf(__expf(-fabsf(acc)));
}

// selective scan, fused with +xc*Dp and *silu(res).
// Lane pair (L, L+32) shares one (b,d): each lane handles 8 of 16 states;
// combine via shfl_xor(32). 256 blocks x 64 threads.
__global__ __launch_bounds__(64) void k_scan(const float* __restrict__ dt,
    const float* __restrict__ xc, const float* __restrict__ xdbl,
    const float* __restrict__ xr, const float* __restrict__ A_log,
    const float* __restrict__ Dp, float* __restrict__ y)
{
    const int lane = threadIdx.x & 63;
    const int half = lane >> 5;                       // 0: n=0..7, 1: n=8..15
    const int p = blockIdx.x * 32 + (lane & 31);      // pair id, 8192 total
    const int b = p >> 10, d = p & 1023;
    float A[8];
    #pragma unroll
    for (int n = 0; n < 8; ++n) A[n] = -__expf(A_log[d * 16 + half * 8 + n]);
    float Dv = Dp[d];
    float h[8] = {};
    const int row0 = b * 64;
    size_t base = (size_t)row0 * 1024 + d;
    float dtv = dt[base], xv = xc[base];
    float res = xr[(size_t)row0 * 2048 + 1024 + d];
    const float4* Bp = (const float4*)&xdbl[(size_t)row0 * 64 + 32 + half * 8];
    const float4* Cq = (const float4*)&xdbl[(size_t)row0 * 64 + 48 + half * 8];
    float4 B0 = Bp[0], B1 = Bp[1];
    float4 C0 = Cq[0], C1 = Cq[1];
    for (int t = 0; t < TT; ++t) {
        float dtv_n = 0.f, xv_n = 0.f, res_n = 0.f;
        float4 B0n = {}, B1n = {}, C0n = {}, C1n = {};
        if (t < TT - 1) {
            size_t b2 = base + (size_t)(t + 1) * 1024;
            dtv_n = dt[b2]; xv_n = xc[b2];
            res_n = xr[(size_t)(row0 + t + 1) * 2048 + 1024 + d];
            const float4* Bp2 = (const float4*)&xdbl[(size_t)(row0 + t + 1) * 64 + 32 + half * 8];
            const float4* Cq2 = (const float4*)&xdbl[(size_t)(row0 + t + 1) * 64 + 48 + half * 8];
            B0n = Bp2[0]; B1n = Bp2[1]; C0n = Cq2[0]; C1n = Cq2[1];
        }
        float dtx = dtv * xv;
        float acch = 0.f;
        #define SCAN_STEP(Bv, Cv, n0)                                             \
        {                                                                         \
            float bb[4] = {Bv.x, Bv.y, Bv.z, Bv.w};                               \
            float cv[4] = {Cv.x, Cv.y, Cv.z, Cv.w};                               \
            _Pragma("unroll")                                                     \
            for (int r = 0; r < 4; ++r) {                                         \
                int n = n0 + r;                                                   \
                float hv = __expf(dtv * A[n]) * h[n] + dtx * bb[r];               \
                h[n] = hv;                                                        \
                acch += hv * cv[r];                                               \
            }                                                                     \
        }
        SCAN_STEP(B0, C0, 0) SCAN_STEP(B1, C1, 4)
        #undef SCAN_STEP
        float acc = acch + __shfl_xor(acch, 32, 64);
        float sil = res / (1.f + __expf(-res));
        if (half == 0)
            y[(size_t)(row0 + t) * 1024 + d] = (acc + xv * Dv) * sil;
        dtv = dtv_n; xv = xv_n; res = res_n;
        B0 = B0n; B1 = B1n; C0 = C0n; C1 = C1n;
    }
}

__global__ __launch_bounds__(256) void k_meant(const float* __restrict__ h,
                                               float* __restrict__ hm)
{
    int idx = blockIdx.x * 256 + threadIdx.x;   // 8*512
    int b = idx >> 9, d = idx & 511;
    const float* p = h + (size_t)b * 64 * 512 + d;
    float s = 0.f;
    for (int t = 0; t < 64; ++t) s += p[t * 512];
    hm[idx] = s * (1.f / 64.f);
}

__global__ __launch_bounds__(256) void k_final(const float* __restrict__ hm,
    const float* __restrict__ fw, const float* __restrict__ fb,
    const float* __restrict__ cw, const float* __restrict__ cb, float* __restrict__ out)
{
    __shared__ float red[4];
    __shared__ float nrm[512];
    int b = blockIdx.x;
    const float* xp = hm + (size_t)b * 512;
    int c2 = threadIdx.x * 2;
    float2 v = *(const float2*)&xp[c2];
    float mu = blockSum(v.x + v.y, red) * (1.f / 512.f);
    float d0 = v.x - mu, d1 = v.y - mu;
    float var = blockSum(d0 * d0 + d1 * d1, red) * (1.f / 512.f);
    float inv = rsqrtf(var + 1e-5f);
    nrm[c2] = d0 * inv * fw[c2] + fb[c2];
    nrm[c2 + 1] = d1 * inv * fw[c2 + 1] + fb[c2 + 1];
    __syncthreads();
    for (int c = 0; c < 11; ++c) {
        float p = nrm[threadIdx.x] * cw[threadIdx.x * 11 + c]
                + nrm[threadIdx.x + 256] * cw[(threadIdx.x + 256) * 11 + c];
        float s = blockSum(p, red);
        if (threadIdx.x == 0) out[b * 11 + c] = s + cb[c];
    }
}

// ---------------- host ----------------

extern "C" void kernel_launch(void* const* d_in, const int* in_sizes, int n_in,
                              void* d_out, int out_size, void* d_ws, size_t ws_size,
                              hipStream_t stream)
{
    const float* x      = (const float*)d_in[0];
    const float* c1w    = (const float*)d_in[1];
    const float* c1b    = (const float*)d_in[2];
    const float* c2w    = (const float*)d_in[3];
    const float* c2b    = (const float*)d_in[4];
    const float* c3w    = (const float*)d_in[5];
    const float* c3b    = (const float*)d_in[6];
    const float* inp_w  = (const float*)d_in[7];
    const float* inp_b  = (const float*)d_in[8];
    const float* ln_w   = (const float*)d_in[9];
    const float* ln_b   = (const float*)d_in[10];
    const float* in_w   = (const float*)d_in[11];
    const float* conv_w = (const float*)d_in[12];
    const float* xproj_w= (const float*)d_in[13];
    const float* dt_w   = (const float*)d_in[14];
    const float* dt_b   = (const float*)d_in[15];
    const float* A_log  = (const float*)d_in[16];
    const float* Dp     = (const float*)d_in[17];
    const float* mb_out_w=(const float*)d_in[18];
    const float* fn_w   = (const float*)d_in[19];
    const float* fn_b   = (const float*)d_in[20];
    const float* cls_w  = (const float*)d_in[21];
    const float* cls_b  = (const float*)d_in[22];
    float* out = (float*)d_out;

    float* ws   = (float*)d_ws;
    float* bufA = ws;                       // 16,777,216 floats (67 MB)
    float* bufB = bufA + 16777216;          // 16,777,216
    float* h    = bufB + 16777216;          // 262,144
    float* hn   = h    + 262144;            // 262,144
    float* xr   = hn   + 262144;            // 1,048,576
    float* xc   = xr   + 1048576;           // 524,288
    float* xdbl = xc   + 524288;            // 32,768
    float* dtb  = xdbl + 32768;             // 524,288
    float* yb   = dtb  + 524288;            // 524,288
    float* hm   = yb   + 524288;            // 4,096

    // frontend
    k_conv1pool<<<512, 256, 0, stream>>>(x, c1w, c1b, bufA);
    k_lif<<<1024, 256, 0, stream>>>(bufA, bufB, 32768);               // -> s1
    k_conv2<<<dim3(4, 512), 256, 0, stream>>>(bufB, c2w, c2b, bufA);  // pooled cur2
    k_lif<<<256, 256, 0, stream>>>(bufA, bufB, 8192);                 // -> s2
    k_conv3<<<dim3(2, 512), 256, 0, stream>>>(bufB, c3w, c3b, bufA);  // cur3
    k_lif3smooth<<<512, 256, 0, stream>>>(bufA, bufB);                // -> act

    // input projection: act(512x16384) @ inp_w(16384x512), split-K=32
    k_gemm<<<dim3(8, 8, 32), 256, 0, stream>>>(bufB, inp_w, bufA, 512, 512, 16384);
    k_reduce<false, true><<<256, 256, 0, stream>>>(bufA, inp_b, h, 262144, 512, 32);

    for (int l = 0; l < 4; ++l) {
        k_ln<<<512, 256, 0, stream>>>(h, ln_w + l * 512, ln_b + l * 512, hn);
        k_gemm<<<dim3(32, 8, 4), 256, 0, stream>>>(hn, in_w + (size_t)l * 1048576, bufA, 512, 2048, 512);
        k_reduce<false, false><<<1024, 256, 0, stream>>>(bufA, nullptr, xr, 1048576, 2048, 4);
        k_convsilu<<<2048, 256, 0, stream>>>(xr, conv_w + l * 4096, xc);
        k_xproj<<<512, 64, 0, stream>>>(xc, xproj_w + l * 65536, xdbl);
        k_dtproj<<<2048, 256, 0, stream>>>(xdbl, dt_w + l * 32768, dt_b + l * 1024, dtb);
        k_scan<<<256, 64, 0, stream>>>(dtb, xc, xdbl, xr, A_log + l * 16384, Dp + l * 1024, yb);
        k_gemm<<<dim3(8, 8, 16), 256, 0, stream>>>(yb, mb_out_w + (size_t)l * 524288, bufA, 512, 512, 1024);
        k_reduce<true, false><<<256, 256, 0, stream>>>(bufA, nullptr, h, 262144, 512, 16);
    }

    k_meant<<<16, 256, 0, stream>>>(h, hm);
    k_final<<<8, 256, 0, stream>>>(hm, fn_w, fn_b, cls_w, cls_b, out);
}